// Round 6
// baseline (863.991 us; speedup 1.0000x reference)
//
#include <hip/hip_runtime.h>

typedef unsigned short u16;
typedef short bf16x8 __attribute__((ext_vector_type(8)));
typedef float f32x4 __attribute__((ext_vector_type(4)));

#define CM 256

__device__ inline u16 f2bf(float f) {
    union { float f; unsigned u; } v; v.f = f;
    unsigned r = v.u + 0x7fffu + ((v.u >> 16) & 1u);
    return (u16)(r >> 16);
}

// ---------------------------------------------------------------------------
// k'' bit-interleave for the stage2->stage3 contraction index (c,e):
//   k''[0,1]=c[0,1]  k''[2]=e[0]  k''[3]=c[2]  k''[4:6]=e[1:3]
//   k''[7]=c[3]      k''[8]=e[4]  k''[9]=c[4]
// kB epilogue stores 8B ushort4; with row-keyed XOR pi = (k''>>3)^(p&7) both
// stores and a3 b128 reads are bank-balanced (R5 measured: conflicts -57%).
// ---------------------------------------------------------------------------

// kP: single prep+LN launch (roles by blockIdx.x):
//  [0,512)    : LayerNorm + dual projection -> a_t/b_t (transposed bf16)
//  [512,1024) : Wo[1024 ce][128 z] fp32 -> Wo_t[z][k''] bf16
//  [1024,1280): norm[i][j] = eps + sum_s mask[s,i]*mask[s,j]
// Roles are independent (no cross-block deps) -> safe in one launch.
__global__ __launch_bounds__(256, 2) void kP(
    const float* __restrict__ m, const float* __restrict__ mask,
    const float* __restrict__ ln_g, const float* __restrict__ ln_b,
    const float* __restrict__ Wa, const float* __restrict__ ba,
    const float* __restrict__ Wb, const float* __restrict__ bb,
    const float* __restrict__ Wo,
    u16* __restrict__ a_t, u16* __restrict__ b_t,
    u16* __restrict__ Wo_t, float* __restrict__ norm_ws)
{
    __shared__ u16 mn_s[64 * 264];   // [local row r][k], stride 264 (pad 8)

    const int bid = blockIdx.x, t = threadIdx.x;

    if (bid >= 1024) {               // ---- norm role ----
        int i = bid - 1024, j = t;
        float acc = 1e-3f;
        for (int s = 0; s < 128; s++)
            acc += mask[s * 256 + i] * mask[s * 256 + j];
        norm_ws[i * 256 + j] = acc;
        return;
    }
    if (bid >= 512) {                // ---- Wo transpose role ----
        int idx = (bid - 512) * 256 + t;    // idx = ce*128 + z (coalesced read)
        int ce = idx >> 7, z = idx & 127;
        int c = ce >> 5, e = ce & 31;
        int kpp = (c & 3) | ((e & 1) << 2) | (((c >> 2) & 1) << 3)
                | (((e >> 1) & 7) << 4) | (((c >> 3) & 1) << 7)
                | ((e >> 4) << 8) | ((c >> 4) << 9);
        Wo_t[z * 1024 + kpp] = f2bf(Wo[idx]);
        return;
    }

    // ---- LN + projection role: block = one i, 64 consecutive s ----
    const int w = t >> 6, lane = t & 63, quad = lane >> 4, lr = lane & 15;
    const int i_idx = bid >> 1;
    const int sh = bid & 1;                  // s = sh*64 + local r

    // W fragments by direct strided loads (Wa/Wb are 32 KB, L2-hot)
    const int n = w * 16 + lr;               // 0..63; wave-uniform Wa/Wb split
    const int cc = n & 31;
    const bool isB = n >= 32;
    const float* Wsrc = isB ? Wb : Wa;
    bf16x8 wf[8];
    for (int ks = 0; ks < 8; ks++)
        for (int j = 0; j < 8; j++)
            wf[ks][j] = (short)f2bf(Wsrc[(ks * 32 + quad * 8 + j) * 32 + cc]);

    const float4 g4  = ((const float4*)ln_g)[lane];
    const float4 be4 = ((const float4*)ln_b)[lane];

    for (int rr = 0; rr < 16; rr++) {
        int r = w * 16 + rr;
        int grow = (sh * 64 + r) * 256 + i_idx;      // flat (s,i) row
        float4 x = ((const float4*)m)[grow * 64 + lane];
        float s1 = x.x + x.y + x.z + x.w;
        float s2 = x.x * x.x + x.y * x.y + x.z * x.z + x.w * x.w;
        for (int off = 32; off; off >>= 1) {
            s1 += __shfl_xor(s1, off);
            s2 += __shfl_xor(s2, off);
        }
        float mu = s1 * (1.f / CM);
        float rstd = rsqrtf(s2 * (1.f / CM) - mu * mu + 1e-5f);
        ushort4 o;
        o.x = f2bf((x.x - mu) * rstd * g4.x + be4.x);
        o.y = f2bf((x.y - mu) * rstd * g4.y + be4.y);
        o.z = f2bf((x.z - mu) * rstd * g4.z + be4.z);
        o.w = f2bf((x.w - mu) * rstd * g4.w + be4.w);
        *(ushort4*)(&mn_s[r * 264 + lane * 4]) = o;
    }
    __syncthreads();

    f32x4 acc[4] = {};
    for (int ks = 0; ks < 8; ks++)
        for (int mt = 0; mt < 4; mt++) {
            bf16x8 af = *(const bf16x8*)(&mn_s[(mt * 16 + lr) * 264 + ks * 32 + quad * 8]);
            acc[mt] = __builtin_amdgcn_mfma_f32_16x16x32_bf16(af, wf[ks], acc[mt], 0, 0, 0);
        }

    const float bv = isB ? bb[cc] : ba[cc];
    u16* dst = isB ? b_t : a_t;
    for (int mt = 0; mt < 4; mt++) {
        int rbase = mt * 16 + quad * 4;          // C/D row base; regs contiguous
        int sbase = sh * 64 + rbase;
        ushort4 o;
        o.x = f2bf((acc[mt][0] + bv) * mask[(sbase + 0) * 256 + i_idx]);
        o.y = f2bf((acc[mt][1] + bv) * mask[(sbase + 1) * 256 + i_idx]);
        o.z = f2bf((acc[mt][2] + bv) * mask[(sbase + 2) * 256 + i_idx]);
        o.w = f2bf((acc[mt][3] + bv) * mask[(sbase + 3) * 256 + i_idx]);
        *(ushort4*)(dst + (i_idx * 32 + cc) * 128 + sbase) = o;
    }
}

// ---------------------------------------------------------------------------
// kB: fused outer-product + Wo projection. Tile 4i x 8j, grid (64,32), 256
// thr. Stage 2: LDS-staged two K=64 halves (R3-proven, no spill). Outer tile
// -> LDS bf16 [32 p][1024 k''] swizzled. Stage 3: M=32,K=1024,N=128 with
// ring prefetch: Wo_t depth-4 (covers ~200cyc L2 latency), a3 LDS depth-2.
// LDS 64 KB -> 2 blocks/CU.
// ---------------------------------------------------------------------------
__global__ __launch_bounds__(256, 2) void kB(
    const u16* __restrict__ a_t, const u16* __restrict__ b_t,
    const u16* __restrict__ Wo_t, const float* __restrict__ bo,
    const float* __restrict__ norm_ws, float* __restrict__ out)
{
    __shared__ __align__(16) u16 smem[32768];     // 65,536 B
    u16* a_s = smem;                  // [128][72]
    u16* b_s = smem + 128 * 72;       // [256][72]
    u16* outer_s = smem;              // overlay after stage 2: [32][1024]

    const int t = threadIdx.x;
    const int w = t >> 6, lane = t & 63, quad = lane >> 4, lr = lane & 15;
    const int wm = w >> 1, wn = w & 1;
    const u16* ag = a_t + blockIdx.x * (128 * 128);
    const u16* bg = b_t + blockIdx.y * (256 * 128);

    // ---- stage 2: two K=64 halves through LDS ----
    f32x4 acc2[4][8] = {};
    for (int kh = 0; kh < 2; kh++) {
        for (int q = 0; q < 4; q++) {
            int flat = q * 2048 + t * 8;          // a: 128 rows x 64 k
            int mm = flat >> 6, kk = flat & 63;
            *(uint4*)(&a_s[mm * 72 + kk]) = *(const uint4*)(ag + mm * 128 + kh * 64 + kk);
        }
        for (int q = 0; q < 8; q++) {
            int flat = q * 2048 + t * 8;          // b: 256 rows x 64 k
            int mm = flat >> 6, kk = flat & 63;
            *(uint4*)(&b_s[mm * 72 + kk]) = *(const uint4*)(bg + mm * 128 + kh * 64 + kk);
        }
        __syncthreads();
        for (int ks = 0; ks < 2; ks++) {
            int k0 = ks * 32 + quad * 8;
            bf16x8 af[4], bfr[8];
            for (int tm = 0; tm < 4; tm++)
                af[tm] = *(const bf16x8*)(&a_s[(wm * 64 + tm * 16 + lr) * 72 + k0]);
            for (int tn = 0; tn < 8; tn++)
                bfr[tn] = *(const bf16x8*)(&b_s[(wn * 128 + tn * 16 + lr) * 72 + k0]);
            for (int tm = 0; tm < 4; tm++)
                for (int tn = 0; tn < 8; tn++)
                    acc2[tm][tn] = __builtin_amdgcn_mfma_f32_16x16x32_bf16(
                        af[tm], bfr[tn], acc2[tm][tn], 0, 0, 0);
        }
        __syncthreads();
    }

    // ---- epilogue stage 2: swizzled packed store to outer_s ----
    // value = outer[c][e]; c = (tm&1)*16+quad*4+reg, e = (tn&1)*16+lr
    for (int tm = 0; tm < 4; tm++)
        for (int tn = 0; tn < 8; tn++) {
            int p  = (wm * 2 + (tm >> 1)) * 8 + wn * 4 + (tn >> 1);
            int cI = (quad & 1) | ((lr >> 1) << 1) | ((quad >> 1) << 4)
                   | ((tn & 1) << 5) | ((tm & 1) << 6);
            int pi = cI ^ (p & 7);
            ushort4 o;
            o.x = f2bf(acc2[tm][tn][0]);
            o.y = f2bf(acc2[tm][tn][1]);
            o.z = f2bf(acc2[tm][tn][2]);
            o.w = f2bf(acc2[tm][tn][3]);
            *(ushort4*)(&outer_s[p * 1024 + pi * 8 + 4 * (lr & 1)]) = o;
        }
    __syncthreads();

    // ---- stage 3: [32 p][1024 k''] @ Wo_t -> [32 p][128 z] ----
    const int n0w = w * 32;
    const u16* wp0 = Wo_t + (n0w + lr) * 1024;
    const u16* wp1 = Wo_t + (n0w + 16 + lr) * 1024;
    f32x4 acc3[2][2] = {};

    bf16x8 br[4][2];                 // Wo_t ring, depth 4
#pragma unroll
    for (int d = 0; d < 4; d++) {
        br[d][0] = *(const bf16x8*)(wp0 + d * 32 + quad * 8);
        br[d][1] = *(const bf16x8*)(wp1 + d * 32 + quad * 8);
    }
    bf16x8 a3c[2], a3n[2];           // outer_s double-buffer, depth 2
    {
        int pi0 = quad ^ (lr & 7);
        a3c[0] = *(const bf16x8*)(&outer_s[lr * 1024 + pi0 * 8]);
        a3c[1] = *(const bf16x8*)(&outer_s[(16 + lr) * 1024 + pi0 * 8]);
    }
#pragma unroll 4
    for (int ks = 0; ks < 32; ks++) {
        const int slot = ks & 3;
        if (ks < 31) {
            int pin = ((ks + 1) * 4 + quad) ^ (lr & 7);
            a3n[0] = *(const bf16x8*)(&outer_s[lr * 1024 + pin * 8]);
            a3n[1] = *(const bf16x8*)(&outer_s[(16 + lr) * 1024 + pin * 8]);
        }
        bf16x8 nb0, nb1;
        if (ks < 28) {
            nb0 = *(const bf16x8*)(wp0 + (ks + 4) * 32 + quad * 8);
            nb1 = *(const bf16x8*)(wp1 + (ks + 4) * 32 + quad * 8);
        }
        acc3[0][0] = __builtin_amdgcn_mfma_f32_16x16x32_bf16(a3c[0], br[slot][0], acc3[0][0], 0, 0, 0);
        acc3[0][1] = __builtin_amdgcn_mfma_f32_16x16x32_bf16(a3c[0], br[slot][1], acc3[0][1], 0, 0, 0);
        acc3[1][0] = __builtin_amdgcn_mfma_f32_16x16x32_bf16(a3c[1], br[slot][0], acc3[1][0], 0, 0, 0);
        acc3[1][1] = __builtin_amdgcn_mfma_f32_16x16x32_bf16(a3c[1], br[slot][1], acc3[1][1], 0, 0, 0);
        if (ks < 28) { br[slot][0] = nb0; br[slot][1] = nb1; }
        if (ks < 31) { a3c[0] = a3n[0]; a3c[1] = a3n[1]; }
    }

    // ---- epilogue: + bo, / norm, store ----
    const int i0 = blockIdx.x * 4, j0 = blockIdx.y * 8;
    for (int mt = 0; mt < 2; mt++)
        for (int reg = 0; reg < 4; reg++) {
            int p = mt * 16 + quad * 4 + reg;
            int ii = i0 + (p >> 3), jj = j0 + (p & 7);
            float nrm = norm_ws[ii * 256 + jj];
            for (int tt = 0; tt < 2; tt++) {
                int z = n0w + tt * 16 + lr;
                out[(ii * 256 + jj) * 128 + z] = (acc3[mt][tt][reg] + bo[z]) / nrm;
            }
        }
}

extern "C" void kernel_launch(void* const* d_in, const int* in_sizes, int n_in,
                              void* d_out, int out_size, void* d_ws, size_t ws_size,
                              hipStream_t stream)
{
    const float* m    = (const float*)d_in[0];
    const float* mask = (const float*)d_in[1];
    const float* ln_g = (const float*)d_in[2];
    const float* ln_b = (const float*)d_in[3];
    const float* Wa   = (const float*)d_in[4];
    const float* ba   = (const float*)d_in[5];
    const float* Wb   = (const float*)d_in[6];
    const float* bb   = (const float*)d_in[7];
    const float* Wo   = (const float*)d_in[8];
    const float* bo   = (const float*)d_in[9];
    float* out = (float*)d_out;

    char* ws = (char*)d_ws;
    u16*   a_t     = (u16*)ws;                        // 2 MB
    u16*   b_t     = (u16*)(ws + 0x200000);           // 2 MB
    u16*   Wo_t    = (u16*)(ws + 0x400000);           // 256 KB
    float* norm_ws = (float*)(ws + 0x440000);         // 256 KB

    hipLaunchKernelGGL(kP, dim3(1280), dim3(256), 0, stream,
                       m, mask, ln_g, ln_b, Wa, ba, Wb, bb, Wo,
                       a_t, b_t, Wo_t, norm_ws);
    hipLaunchKernelGGL(kB, dim3(64, 32), dim3(256), 0, stream,
                       a_t, b_t, Wo_t, bo, norm_ws, out);
}